// Round 18
// baseline (316.785 us; speedup 1.0000x reference)
//
#include <hip/hip_runtime.h>

#define BB 32
#define NN 256
#define DIN 512
#define DD 256
#define HH 512
#define MM 8192      // BB*NN
#define KSTR 16

typedef __attribute__((ext_vector_type(8))) __bf16 bf16x8;
typedef __attribute__((ext_vector_type(4))) float f32x4;
typedef unsigned short ushort_t;

typedef const float __attribute__((address_space(1)))* gas1f;
typedef const unsigned int __attribute__((address_space(1)))* gas1u;
typedef unsigned int __attribute__((address_space(3)))* las3u;

__device__ __forceinline__ unsigned short f2bf(float x) {
  unsigned u = __float_as_uint(x);
  u += 0x7FFFu + ((u >> 16) & 1u);   // round-to-nearest-even
  return (unsigned short)(u >> 16);
}

// ---------------- K1 v3: xie = xi @ W_img + b_img (R16 verbatim) --------------
__global__ __launch_bounds__(512, 4) void k_enc(const float* __restrict__ A,
                                                const float* __restrict__ W,
                                                const float* __restrict__ bias,
                                                float* __restrict__ C,
                                                ushort_t* __restrict__ A_bf,
                                                float* __restrict__ xieT,
                                                float* __restrict__ x2g) {
  __shared__ float Asm[16][520];
  const int tid = threadIdx.x;
  const int mb0 = blockIdx.x * 16;
  const int cg = tid & 63;          // 64 col-groups x 4 cols
  const int mh = (tid >> 6) & 3;    // 4 row-groups x 4 rows (wave-uniform)
  const int team = tid >> 8;        // 2 k-teams of 256
#pragma unroll
  for (int i = 0; i < 4; ++i) {
    int idx = tid + i * 512;          // 2048 quads = 16 rows x 128
    int m = idx >> 7;
    int kq = idx & 127;
    float4 v = *reinterpret_cast<const float4*>(&A[(size_t)(mb0 + m) * DIN + kq * 4]);
    *reinterpret_cast<float4*>(&Asm[m][kq * 4]) = v;
  }
  __syncthreads();
  float4 acc[4] = {};
  const int kt0 = team * 256;
  const float* wp = &W[(size_t)kt0 * DD + cg * 4];
  float4 wA[4], wB[4];
#pragma unroll
  for (int j = 0; j < 4; ++j)
    wA[j] = *reinterpret_cast<const float4*>(&wp[(size_t)j * DD]);
  for (int it = 0; it < 64; ++it) {
    if (it < 63) {
#pragma unroll
      for (int j = 0; j < 4; ++j)
        wB[j] = *reinterpret_cast<const float4*>(&wp[(size_t)((it + 1) * 4 + j) * DD]);
    }
    const int kk = kt0 + it * 4;
#pragma unroll
    for (int r = 0; r < 4; ++r) {
      float4 a = *reinterpret_cast<const float4*>(&Asm[mh * 4 + r][kk]);
      acc[r].x += a.x * wA[0].x; acc[r].y += a.x * wA[0].y;
      acc[r].z += a.x * wA[0].z; acc[r].w += a.x * wA[0].w;
      acc[r].x += a.y * wA[1].x; acc[r].y += a.y * wA[1].y;
      acc[r].z += a.y * wA[1].z; acc[r].w += a.y * wA[1].w;
      acc[r].x += a.z * wA[2].x; acc[r].y += a.z * wA[2].y;
      acc[r].z += a.z * wA[2].z; acc[r].w += a.z * wA[2].w;
      acc[r].x += a.w * wA[3].x; acc[r].y += a.w * wA[3].y;
      acc[r].z += a.w * wA[3].z; acc[r].w += a.w * wA[3].w;
    }
#pragma unroll
    for (int j = 0; j < 4; ++j) wA[j] = wB[j];
  }
  __syncthreads();
  float* red = &Asm[0][0];
  if (team == 1) {
#pragma unroll
    for (int r = 0; r < 4; ++r)
      *reinterpret_cast<float4*>(&red[(mh * 4 + r) * 256 + cg * 4]) = acc[r];
  }
  __syncthreads();
  if (team == 0) {
    float4 bv = *reinterpret_cast<const float4*>(&bias[cg * 4]);
#pragma unroll
    for (int r = 0; r < 4; ++r) {
      const int row = mb0 + mh * 4 + r;
      float4 o = *reinterpret_cast<float4*>(&red[(mh * 4 + r) * 256 + cg * 4]);
      float4 s;
      s.x = acc[r].x + o.x + bv.x;
      s.y = acc[r].y + o.y + bv.y;
      s.z = acc[r].z + o.z + bv.z;
      s.w = acc[r].w + o.w + bv.w;
      *reinterpret_cast<float4*>(&C[(size_t)row * DD + cg * 4]) = s;
      ushort4 ob;
      ob.x = f2bf(s.x); ob.y = f2bf(s.y); ob.z = f2bf(s.z); ob.w = f2bf(s.w);
      *reinterpret_cast<ushort4*>(&A_bf[(size_t)row * 512 + cg * 4]) = ob;
      *reinterpret_cast<float4*>(&red[(mh * 4 + r) * 256 + cg * 4]) = s;
    }
  }
  __syncthreads();
  // norm phase (bitwise-identical per-row expression + 64-lane tree)
  {
    const int lane = tid & 63;
    const int w8 = tid >> 6;          // 8 waves x 2 rows = 16 rows
#pragma unroll
    for (int rr = 0; rr < 2; ++rr) {
      const int row = w8 * 2 + rr;
      float4 v = *reinterpret_cast<const float4*>(&red[row * 256 + lane * 4]);
      float s = v.x * v.x + v.y * v.y + v.z * v.z + v.w * v.w;
#pragma unroll
      for (int off = 1; off < 64; off <<= 1) s += __shfl_xor(s, off);
      if (lane == 0) x2g[mb0 + row] = s;
    }
  }
  // transposed copy: xieT[b][d][n] (pure copy)
  {
    const int b = mb0 >> 8;
    const int n0b = mb0 & 255;
    const int d = tid >> 1;           // 256 d
    const int nh = (tid & 1) * 8;     // 2 chunks x 8 n = 16 rows
    float tmp[8];
#pragma unroll
    for (int i = 0; i < 8; ++i) tmp[i] = red[(nh + i) * 256 + d];
    float* dst = &xieT[((size_t)b * 256 + d) * 256 + n0b + nh];
    *reinterpret_cast<float4*>(&dst[0]) = *reinterpret_cast<float4*>(&tmp[0]);
    *reinterpret_cast<float4*>(&dst[4]) = *reinterpret_cast<float4*>(&tmp[4]);
  }
}

// ------- K2 v7: d2 + in-reg topk + agg + cvtw (R16 verbatim) ------------------
__global__ __launch_bounds__(512, 4) void k_dist(const float* __restrict__ xie,
                                                 const float* __restrict__ xieT,
                                                 const float* __restrict__ x2g,
                                                 const int* __restrict__ kp,
                                                 ushort_t* __restrict__ A_bf,
                                                 const float* __restrict__ Ws,
                                                 const float* __restrict__ Wn,
                                                 ushort_t* __restrict__ B_bfT) {
  __shared__ float Asm[16][260];
  __shared__ int nbrL[16][KSTR];
  const int tid = threadIdx.x;
  const int b = blockIdx.x >> 4;
  const int n0b = (blockIdx.x & 15) * 16;
  const int base = b * 256;
  const int cg = tid & 63;          // 64 col-groups x 4 m = 256 m
  const int rg = tid >> 6;          // 8 row-groups x 2 rows (wave-uniform)
  const int kcnt = kp[0];
#pragma unroll
  for (int i = 0; i < 2; ++i) {
    int idx = tid + i * 512;        // 1024 quads = 16 rows x 64
    int m = idx >> 6;
    int kq = idx & 63;
    float4 v = *reinterpret_cast<const float4*>(
        &xie[(size_t)(base + n0b + m) * DD + kq * 4]);
    *reinterpret_cast<float4*>(&Asm[m][kq * 4]) = v;
  }
  __syncthreads();
  float4 acc[2] = {};               // [r] x 4 m
  const float* wp = &xieT[(size_t)base * 256 + cg * 4];
  float4 wA[4], wB[4];
#pragma unroll
  for (int j = 0; j < 4; ++j)
    wA[j] = *reinterpret_cast<const float4*>(&wp[(size_t)j * 256]);
  for (int it = 0; it < 64; ++it) {
    if (it < 63) {
#pragma unroll
      for (int j = 0; j < 4; ++j)
        wB[j] = *reinterpret_cast<const float4*>(&wp[(size_t)((it + 1) * 4 + j) * 256]);
    }
#pragma unroll
    for (int r = 0; r < 2; ++r) {
      float4 a = *reinterpret_cast<const float4*>(&Asm[rg * 2 + r][it * 4]);
      acc[r].x += a.x * wA[0].x; acc[r].y += a.x * wA[0].y;
      acc[r].z += a.x * wA[0].z; acc[r].w += a.x * wA[0].w;
      acc[r].x += a.y * wA[1].x; acc[r].y += a.y * wA[1].y;
      acc[r].z += a.y * wA[1].z; acc[r].w += a.y * wA[1].w;
      acc[r].x += a.z * wA[2].x; acc[r].y += a.z * wA[2].y;
      acc[r].z += a.z * wA[2].z; acc[r].w += a.z * wA[2].w;
      acc[r].x += a.w * wA[3].x; acc[r].y += a.w * wA[3].y;
      acc[r].z += a.w * wA[3].z; acc[r].w += a.w * wA[3].w;
    }
#pragma unroll
    for (int j = 0; j < 4; ++j) wA[j] = wB[j];
  }
  // d2 in registers (identical expression; chain per output unchanged)
  float v[2][4];
#pragma unroll
  for (int r = 0; r < 2; ++r) {
    const int nl = n0b + rg * 2 + r;
    const float xn = x2g[base + nl];
    const float* accp = reinterpret_cast<const float*>(&acc[r]);
#pragma unroll
    for (int j2 = 0; j2 < 4; ++j2) {
      const int mc = cg * 4 + j2;
      float dv = xn + x2g[base + mc] - 2.0f * accp[j2];
      if (nl == mc) dv = 1e30f;
      v[r][j2] = dv;
    }
  }
  // top-k per row: lexicographic (value, index) min over the full 64-lane wave
#pragma unroll
  for (int r = 0; r < 2; ++r) {
    for (int it2 = 0; it2 < kcnt; ++it2) {
      float lv = v[r][0]; int li = 0;
#pragma unroll
      for (int j = 1; j < 4; ++j)
        if (v[r][j] < lv) { lv = v[r][j]; li = j; }
      int midx = cg * 4 + li;
#pragma unroll
      for (int off = 1; off < 64; off <<= 1) {
        float ov = __shfl_xor(lv, off);
        int oi = __shfl_xor(midx, off);
        if (ov < lv || (ov == lv && oi < midx)) { lv = ov; midx = oi; }
      }
      if (cg == 0) nbrL[rg * 2 + r][it2] = midx;
      const bool mine = (cg == (midx >> 2));
      const int jw = midx & 3;
#pragma unroll
      for (int j = 0; j < 4; ++j)
        v[r][j] = (mine && j == jw) ? 3e38f : v[r][j];
    }
  }
  __syncthreads();
  // agg: thread = (row, 8-float chunk): 512 thr = 16 rows x 32 chunks
  {
    const int row = tid >> 5;
    const int q0 = (tid & 31) * 8;
    float4 a4[2] = {};
    for (int j = 0; j < kcnt; ++j) {
      const int nb = nbrL[row][j];
      const float* src = &xie[(size_t)(base + nb) * DD + q0];
      float4 v0 = *reinterpret_cast<const float4*>(&src[0]);
      float4 v1 = *reinterpret_cast<const float4*>(&src[4]);
      a4[0].x += v0.x; a4[0].y += v0.y; a4[0].z += v0.z; a4[0].w += v0.w;
      a4[1].x += v1.x; a4[1].y += v1.y; a4[1].z += v1.z; a4[1].w += v1.w;
    }
    const float sc = 1.0f / (float)kcnt;
    ushort_t ob[8];
#pragma unroll
    for (int q = 0; q < 2; ++q) {
      ob[q * 4 + 0] = f2bf(a4[q].x * sc);
      ob[q * 4 + 1] = f2bf(a4[q].y * sc);
      ob[q * 4 + 2] = f2bf(a4[q].z * sc);
      ob[q * 4 + 3] = f2bf(a4[q].w * sc);
    }
    ushort_t* dst = &A_bf[(size_t)(base + n0b + row) * 512 + 256 + q0];
    *reinterpret_cast<uint4*>(&dst[0]) = *reinterpret_cast<uint4*>(&ob[0]);
  }
  // cvtw tail: 512 blocks x first 256 thr = 131072 elems
  if (tid < 256) {
    const int id = blockIdx.x * 256 + tid;
    const int k = id >> 8;
    const int n = id & 255;
    float vw = (k < 256) ? Ws[(size_t)k * 256 + n] : Wn[(size_t)(k - 256) * 256 + n];
    B_bfT[(size_t)n * 512 + k] = f2bf(vw);
  }
}

// ---------------- K4: gep = relu(A_bf @ B_bfT^T + b) (R16 verbatim) -----------
__global__ __launch_bounds__(256) void k_gnn(const ushort_t* __restrict__ A_bf,
                                             const ushort_t* __restrict__ B_bfT,
                                             const float* __restrict__ bias,
                                             float* __restrict__ C,
                                             ushort_t* __restrict__ gep_bf) {
  __shared__ ushort_t As[64 * 72];
  __shared__ ushort_t Bs[64 * 72];
  const int tid = threadIdx.x;
  const int m0 = blockIdx.x * 64, n0 = blockIdx.y * 64;
  const int l = tid & 63, w = tid >> 6;
  const int mw = (w & 1) * 32, nw = (w >> 1) * 32;
  const int lr = tid >> 3, lq = tid & 7;
  f32x4 acc[2][2] = {};
  for (int kt = 0; kt < 8; ++kt) {
    const int kb = kt * 64;
#pragma unroll
    for (int s = 0; s < 2; ++s) {
      const int r = lr + s * 32;
      uint4 va = *reinterpret_cast<const uint4*>(&A_bf[(size_t)(m0 + r) * 512 + kb + lq * 8]);
      *reinterpret_cast<uint4*>(&As[r * 72 + lq * 8]) = va;
      uint4 vb = *reinterpret_cast<const uint4*>(&B_bfT[(size_t)(n0 + r) * 512 + kb + lq * 8]);
      *reinterpret_cast<uint4*>(&Bs[r * 72 + lq * 8]) = vb;
    }
    __syncthreads();
#pragma unroll
    for (int ks = 0; ks < 2; ++ks) {
      bf16x8 af[2], bf[2];
#pragma unroll
      for (int mi = 0; mi < 2; ++mi)
        af[mi] = *reinterpret_cast<const bf16x8*>(
            &As[(mw + mi * 16 + (l & 15)) * 72 + ks * 32 + (l >> 4) * 8]);
#pragma unroll
      for (int ni = 0; ni < 2; ++ni)
        bf[ni] = *reinterpret_cast<const bf16x8*>(
            &Bs[(nw + ni * 16 + (l & 15)) * 72 + ks * 32 + (l >> 4) * 8]);
#pragma unroll
      for (int mi = 0; mi < 2; ++mi)
#pragma unroll
        for (int ni = 0; ni < 2; ++ni)
          acc[mi][ni] = __builtin_amdgcn_mfma_f32_16x16x32_bf16(af[mi], bf[ni],
                                                                acc[mi][ni], 0, 0, 0);
    }
    __syncthreads();
  }
#pragma unroll
  for (int mi = 0; mi < 2; ++mi) {
    const int row_base = m0 + mw + mi * 16 + (l >> 4) * 4;
#pragma unroll
    for (int ni = 0; ni < 2; ++ni) {
      const int col = n0 + nw + ni * 16 + (l & 15);
      const float bv = bias[col];
#pragma unroll
      for (int r = 0; r < 4; ++r) {
        float v = acc[mi][ni][r] + bv;
        v = v > 0.0f ? v : 0.0f;
        C[(size_t)(row_base + r) * 256 + col] = v;
        gep_bf[(size_t)(row_base + r) * 256 + col] = f2bf(v);
      }
    }
  }
}

// ------- K5 v4 (R13-R16): column-split, 2 blocks/CU ---------------------------
__global__ __launch_bounds__(256) void k_mlp1(const ushort_t* __restrict__ gep_bf,
                                              const float* __restrict__ W1,
                                              float* __restrict__ part) {
  __shared__ ushort_t WbT[2][256][40];       // [buf][col][32k + pad8]
  __shared__ ushort_t Ab[32][264];           // 32 rows x 256 k
  const int tid = threadIdx.x;
  const int b = blockIdx.x >> 1;
  const int ch = blockIdx.x & 1;
  const int l = tid & 63, w = tid >> 6;
#pragma unroll
  for (int i = 0; i < 4; ++i) {              // stage A (16 KB)
    int id = tid + i * 256;
    int m = id >> 5, dq8 = (id & 31) * 8;
    *reinterpret_cast<uint4*>(&Ab[m][dq8]) = *reinterpret_cast<const uint4*>(
        &gep_bf[((size_t)m * 256 + b) * 256 + dq8]);
  }
  const float* Wbase = W1 + (size_t)b * 256 * 512 + ch * 256 + tid;  // col = tid
  float wreg[32];
  auto WLOAD = [&](int s) {
#pragma unroll
    for (int kk = 0; kk < 32; ++kk)
      wreg[kk] = Wbase[(size_t)(s * 32 + kk) * 512];
  };
  auto WSTORE = [&](int buf) {
#pragma unroll
    for (int q = 0; q < 4; ++q) {
      ushort_t tmp[8];
#pragma unroll
      for (int j = 0; j < 8; ++j) tmp[j] = f2bf(wreg[q * 8 + j]);
      *reinterpret_cast<uint4*>(&WbT[buf][tid][q * 8]) =
          *reinterpret_cast<const uint4*>(tmp);
    }
  };
  WLOAD(0);
  WSTORE(0);
  __syncthreads();
  const int n0w = w * 64;
  f32x4 acc[2][4] = {};
  for (int s = 0; s < 8; ++s) {
    const int cur = s & 1;
    if (s < 7) WLOAD(s + 1);
    bf16x8 a[2], bw[4];
#pragma unroll
    for (int mi = 0; mi < 2; ++mi)
      a[mi] = *reinterpret_cast<const bf16x8*>(
          &Ab[mi * 16 + (l & 15)][s * 32 + (l >> 4) * 8]);
#pragma unroll
    for (int nf = 0; nf < 4; ++nf)
      bw[nf] = *reinterpret_cast<const bf16x8*>(
          &WbT[cur][n0w + nf * 16 + (l & 15)][(l >> 4) * 8]);
#pragma unroll
    for (int mi = 0; mi < 2; ++mi)
#pragma unroll
      for (int nf = 0; nf < 4; ++nf)
        acc[mi][nf] = __builtin_amdgcn_mfma_f32_16x16x32_bf16(a[mi], bw[nf],
                                                              acc[mi][nf], 0, 0, 0);
    if (s < 7) {
      WSTORE(cur ^ 1);
      __syncthreads();
    }
  }
#pragma unroll
  for (int mi = 0; mi < 2; ++mi)
#pragma unroll
    for (int nf = 0; nf < 4; ++nf) {
      const int col = ch * 256 + n0w + nf * 16 + (l & 15);
#pragma unroll
      for (int r = 0; r < 4; ++r) {
        const int m = mi * 16 + (l >> 4) * 4 + r;
        part[((size_t)b * 32 + m) * HH + col] = acc[mi][nf][r];
      }
    }
}

// ------- K6a: hpart (R16 verbatim) --------------------------------------------
__global__ __launch_bounds__(256) void k_hred(const float* __restrict__ part,
                                              float* __restrict__ hpart) {
  const int tid = threadIdx.x;
  const int m = blockIdx.x >> 3;           // 0..31
  const int s = blockIdx.x & 7;            // 0..7 (bb slice of 32)
  const int c0 = tid * 2;
  float a0 = 0.f, a1 = 0.f;
  for (int bb = s * 32; bb < s * 32 + 32; ++bb) {
    float2 v = *reinterpret_cast<const float2*>(&part[((size_t)bb * 32 + m) * 512 + c0]);
    a0 += v.x; a1 += v.y;
  }
  float2 o; o.x = a0; o.y = a1;
  *reinterpret_cast<float2*>(&hpart[((size_t)s * 32 + m) * 512 + c0]) = o;
}

// ------- K6b: out (R16 verbatim) ----------------------------------------------
__global__ __launch_bounds__(256) void k_out2(const float* __restrict__ hpart,
                                              const float* __restrict__ b1,
                                              const float* __restrict__ W2,
                                              const float* __restrict__ b2,
                                              float* __restrict__ outp) {
  __shared__ float red[4];
  const int tid = threadIdx.x;
  const int m = blockIdx.x;
  const int c0 = tid * 2;
  float a0 = 0.f, a1 = 0.f;
#pragma unroll
  for (int s = 0; s < 8; ++s) {
    float2 v = *reinterpret_cast<const float2*>(&hpart[((size_t)s * 32 + m) * 512 + c0]);
    a0 += v.x; a1 += v.y;
  }
  float h0 = a0 + b1[c0];
  float h1 = a1 + b1[c0 + 1];
  h0 = h0 > 0.f ? h0 : 0.f;
  h1 = h1 > 0.f ? h1 : 0.f;
  float val = h0 * W2[c0] + h1 * W2[c0 + 1];
#pragma unroll
  for (int off = 1; off < 64; off <<= 1) val += __shfl_xor(val, off);
  const int w = tid >> 6;
  if ((tid & 63) == 0) red[w] = val;
  __syncthreads();
  if (tid == 0) outp[m] = red[0] + red[1] + red[2] + red[3] + b2[0];
}

extern "C" void kernel_launch(void* const* d_in, const int* in_sizes, int n_in,
                              void* d_out, int out_size, void* d_ws, size_t ws_size,
                              hipStream_t stream) {
  const float* xi     = (const float*)d_in[0];
  const float* W_img  = (const float*)d_in[1];
  const float* b_img  = (const float*)d_in[2];
  const float* W_self = (const float*)d_in[3];
  const float* W_nbr  = (const float*)d_in[4];
  const float* b_gnn  = (const float*)d_in[5];
  const float* W1     = (const float*)d_in[6];
  const float* b1     = (const float*)d_in[7];
  const float* W2     = (const float*)d_in[8];
  const float* b2     = (const float*)d_in[9];
  const int*   kp     = (const int*)d_in[10];

  float* xie  = (float*)d_out;
  float* gep  = xie + (size_t)MM * DD;
  float* outp = gep + (size_t)MM * DD;

  float* ws   = (float*)d_ws;
  float* x2   = ws;                                   // 8,192 f
  float* part = ws + 8192;                            // 4,194,304 f
  float* xieT = part + (size_t)4194304;               // 2,097,152 f
  float* hpart = xieT + (size_t)2097152;              // 131,072 f
  ushort_t* A_bf   = (ushort_t*)(hpart + 131072);     // 8192*512 us
  ushort_t* B_bfT  = A_bf + (size_t)MM * 512;         // 131,072 us
  ushort_t* gep_bf = B_bfT + 131072;                  // 2,097,152 us

  // MEASUREMENT: k_enc x3 and k_dist x3 (both idempotent pure functions).
  // dur ~= base(135.3) + 2*(E + D) + ~4 us of extra gaps.
  k_enc  <<<MM / 16, 512, 0, stream>>>(xi, W_img, b_img, xie, A_bf, xieT, x2);
  k_enc  <<<MM / 16, 512, 0, stream>>>(xi, W_img, b_img, xie, A_bf, xieT, x2);
  k_enc  <<<MM / 16, 512, 0, stream>>>(xi, W_img, b_img, xie, A_bf, xieT, x2);
  k_dist <<<512, 512, 0, stream>>>(xie, xieT, x2, kp, A_bf, W_self, W_nbr, B_bfT);
  k_dist <<<512, 512, 0, stream>>>(xie, xieT, x2, kp, A_bf, W_self, W_nbr, B_bfT);
  k_dist <<<512, 512, 0, stream>>>(xie, xieT, x2, kp, A_bf, W_self, W_nbr, B_bfT);
  k_gnn  <<<dim3(128, 4), 256, 0, stream>>>(A_bf, B_bfT, b_gnn, gep, gep_bf);
  k_mlp1 <<<512, 256, 0, stream>>>(gep_bf, W1, part);
  k_hred <<<256, 256, 0, stream>>>(part, hpart);
  k_out2 <<<BB, 256, 0, stream>>>(hpart, b1, W2, b2, outp);
}

// Round 22
// 134.623 us; speedup vs baseline: 2.3531x; 2.3531x over previous
//
#include <hip/hip_runtime.h>

#define BB 32
#define NN 256
#define DIN 512
#define DD 256
#define HH 512
#define MM 8192      // BB*NN
#define KSTR 16

typedef __attribute__((ext_vector_type(8))) __bf16 bf16x8;
typedef __attribute__((ext_vector_type(4))) float f32x4;
typedef unsigned short ushort_t;

typedef const float __attribute__((address_space(1)))* gas1f;
typedef const unsigned int __attribute__((address_space(1)))* gas1u;
typedef unsigned int __attribute__((address_space(3)))* las3u;

__device__ __forceinline__ unsigned short f2bf(float x) {
  unsigned u = __float_as_uint(x);
  u += 0x7FFFu + ((u >> 16) & 1u);   // round-to-nearest-even
  return (unsigned short)(u >> 16);
}

// ---------------- K1 v3: xie = xi @ W_img + b_img (R16 verbatim, passed) ------
// 16-row blocks (512 blocks) -> 33 KB LDS -> 2 blocks/CU. W in REGISTERS
// (LOCKED: LDS-staged W variants change low-order bits -> KNN tie flip).
__global__ __launch_bounds__(512, 4) void k_enc(const float* __restrict__ A,
                                                const float* __restrict__ W,
                                                const float* __restrict__ bias,
                                                float* __restrict__ C,
                                                ushort_t* __restrict__ A_bf,
                                                float* __restrict__ xieT,
                                                float* __restrict__ x2g) {
  __shared__ float Asm[16][520];
  const int tid = threadIdx.x;
  const int mb0 = blockIdx.x * 16;
  const int cg = tid & 63;          // 64 col-groups x 4 cols
  const int mh = (tid >> 6) & 3;    // 4 row-groups x 4 rows (wave-uniform)
  const int team = tid >> 8;        // 2 k-teams of 256
#pragma unroll
  for (int i = 0; i < 4; ++i) {
    int idx = tid + i * 512;          // 2048 quads = 16 rows x 128
    int m = idx >> 7;
    int kq = idx & 127;
    float4 v = *reinterpret_cast<const float4*>(&A[(size_t)(mb0 + m) * DIN + kq * 4]);
    *reinterpret_cast<float4*>(&Asm[m][kq * 4]) = v;
  }
  __syncthreads();
  float4 acc[4] = {};
  const int kt0 = team * 256;
  const float* wp = &W[(size_t)kt0 * DD + cg * 4];
  float4 wA[4], wB[4];
#pragma unroll
  for (int j = 0; j < 4; ++j)
    wA[j] = *reinterpret_cast<const float4*>(&wp[(size_t)j * DD]);
  for (int it = 0; it < 64; ++it) {
    if (it < 63) {
#pragma unroll
      for (int j = 0; j < 4; ++j)
        wB[j] = *reinterpret_cast<const float4*>(&wp[(size_t)((it + 1) * 4 + j) * DD]);
    }
    const int kk = kt0 + it * 4;
#pragma unroll
    for (int r = 0; r < 4; ++r) {
      float4 a = *reinterpret_cast<const float4*>(&Asm[mh * 4 + r][kk]);
      acc[r].x += a.x * wA[0].x; acc[r].y += a.x * wA[0].y;
      acc[r].z += a.x * wA[0].z; acc[r].w += a.x * wA[0].w;
      acc[r].x += a.y * wA[1].x; acc[r].y += a.y * wA[1].y;
      acc[r].z += a.y * wA[1].z; acc[r].w += a.y * wA[1].w;
      acc[r].x += a.z * wA[2].x; acc[r].y += a.z * wA[2].y;
      acc[r].z += a.z * wA[2].z; acc[r].w += a.z * wA[2].w;
      acc[r].x += a.w * wA[3].x; acc[r].y += a.w * wA[3].y;
      acc[r].z += a.w * wA[3].z; acc[r].w += a.w * wA[3].w;
    }
#pragma unroll
    for (int j = 0; j < 4; ++j) wA[j] = wB[j];
  }
  __syncthreads();
  float* red = &Asm[0][0];
  if (team == 1) {
#pragma unroll
    for (int r = 0; r < 4; ++r)
      *reinterpret_cast<float4*>(&red[(mh * 4 + r) * 256 + cg * 4]) = acc[r];
  }
  __syncthreads();
  if (team == 0) {
    float4 bv = *reinterpret_cast<const float4*>(&bias[cg * 4]);
#pragma unroll
    for (int r = 0; r < 4; ++r) {
      const int row = mb0 + mh * 4 + r;
      float4 o = *reinterpret_cast<float4*>(&red[(mh * 4 + r) * 256 + cg * 4]);
      float4 s;
      s.x = acc[r].x + o.x + bv.x;
      s.y = acc[r].y + o.y + bv.y;
      s.z = acc[r].z + o.z + bv.z;
      s.w = acc[r].w + o.w + bv.w;
      *reinterpret_cast<float4*>(&C[(size_t)row * DD + cg * 4]) = s;
      ushort4 ob;
      ob.x = f2bf(s.x); ob.y = f2bf(s.y); ob.z = f2bf(s.z); ob.w = f2bf(s.w);
      *reinterpret_cast<ushort4*>(&A_bf[(size_t)row * 512 + cg * 4]) = ob;
      *reinterpret_cast<float4*>(&red[(mh * 4 + r) * 256 + cg * 4]) = s;
    }
  }
  __syncthreads();
  // norm phase (bitwise-identical per-row expression + 64-lane tree)
  {
    const int lane = tid & 63;
    const int w8 = tid >> 6;          // 8 waves x 2 rows = 16 rows
#pragma unroll
    for (int rr = 0; rr < 2; ++rr) {
      const int row = w8 * 2 + rr;
      float4 v = *reinterpret_cast<const float4*>(&red[row * 256 + lane * 4]);
      float s = v.x * v.x + v.y * v.y + v.z * v.z + v.w * v.w;
#pragma unroll
      for (int off = 1; off < 64; off <<= 1) s += __shfl_xor(s, off);
      if (lane == 0) x2g[mb0 + row] = s;
    }
  }
  // transposed copy: xieT[b][d][n] (pure copy)
  {
    const int b = mb0 >> 8;
    const int n0b = mb0 & 255;
    const int d = tid >> 1;           // 256 d
    const int nh = (tid & 1) * 8;     // 2 chunks x 8 n = 16 rows
    float tmp[8];
#pragma unroll
    for (int i = 0; i < 8; ++i) tmp[i] = red[(nh + i) * 256 + d];
    float* dst = &xieT[((size_t)b * 256 + d) * 256 + n0b + nh];
    *reinterpret_cast<float4*>(&dst[0]) = *reinterpret_cast<float4*>(&tmp[0]);
    *reinterpret_cast<float4*>(&dst[4]) = *reinterpret_cast<float4*>(&tmp[4]);
  }
}

// ------- K2 v7: d2 + in-reg topk + agg + cvtw (R16 verbatim, passed) ----------
__global__ __launch_bounds__(512, 4) void k_dist(const float* __restrict__ xie,
                                                 const float* __restrict__ xieT,
                                                 const float* __restrict__ x2g,
                                                 const int* __restrict__ kp,
                                                 ushort_t* __restrict__ A_bf,
                                                 const float* __restrict__ Ws,
                                                 const float* __restrict__ Wn,
                                                 ushort_t* __restrict__ B_bfT) {
  __shared__ float Asm[16][260];
  __shared__ int nbrL[16][KSTR];
  const int tid = threadIdx.x;
  const int b = blockIdx.x >> 4;
  const int n0b = (blockIdx.x & 15) * 16;
  const int base = b * 256;
  const int cg = tid & 63;          // 64 col-groups x 4 m = 256 m
  const int rg = tid >> 6;          // 8 row-groups x 2 rows (wave-uniform)
  const int kcnt = kp[0];
#pragma unroll
  for (int i = 0; i < 2; ++i) {
    int idx = tid + i * 512;        // 1024 quads = 16 rows x 64
    int m = idx >> 6;
    int kq = idx & 63;
    float4 v = *reinterpret_cast<const float4*>(
        &xie[(size_t)(base + n0b + m) * DD + kq * 4]);
    *reinterpret_cast<float4*>(&Asm[m][kq * 4]) = v;
  }
  __syncthreads();
  float4 acc[2] = {};               // [r] x 4 m
  const float* wp = &xieT[(size_t)base * 256 + cg * 4];
  float4 wA[4], wB[4];
#pragma unroll
  for (int j = 0; j < 4; ++j)
    wA[j] = *reinterpret_cast<const float4*>(&wp[(size_t)j * 256]);
  for (int it = 0; it < 64; ++it) {
    if (it < 63) {
#pragma unroll
      for (int j = 0; j < 4; ++j)
        wB[j] = *reinterpret_cast<const float4*>(&wp[(size_t)((it + 1) * 4 + j) * 256]);
    }
#pragma unroll
    for (int r = 0; r < 2; ++r) {
      float4 a = *reinterpret_cast<const float4*>(&Asm[rg * 2 + r][it * 4]);
      acc[r].x += a.x * wA[0].x; acc[r].y += a.x * wA[0].y;
      acc[r].z += a.x * wA[0].z; acc[r].w += a.x * wA[0].w;
      acc[r].x += a.y * wA[1].x; acc[r].y += a.y * wA[1].y;
      acc[r].z += a.y * wA[1].z; acc[r].w += a.y * wA[1].w;
      acc[r].x += a.z * wA[2].x; acc[r].y += a.z * wA[2].y;
      acc[r].z += a.z * wA[2].z; acc[r].w += a.z * wA[2].w;
      acc[r].x += a.w * wA[3].x; acc[r].y += a.w * wA[3].y;
      acc[r].z += a.w * wA[3].z; acc[r].w += a.w * wA[3].w;
    }
#pragma unroll
    for (int j = 0; j < 4; ++j) wA[j] = wB[j];
  }
  // d2 in registers (LOCKED expression)
  float v[2][4];
#pragma unroll
  for (int r = 0; r < 2; ++r) {
    const int nl = n0b + rg * 2 + r;
    const float xn = x2g[base + nl];
    const float* accp = reinterpret_cast<const float*>(&acc[r]);
#pragma unroll
    for (int j2 = 0; j2 < 4; ++j2) {
      const int mc = cg * 4 + j2;
      float dv = xn + x2g[base + mc] - 2.0f * accp[j2];
      if (nl == mc) dv = 1e30f;
      v[r][j2] = dv;
    }
  }
  // top-k per row: lexicographic (value, index) min over the full 64-lane wave
#pragma unroll
  for (int r = 0; r < 2; ++r) {
    for (int it2 = 0; it2 < kcnt; ++it2) {
      float lv = v[r][0]; int li = 0;
#pragma unroll
      for (int j = 1; j < 4; ++j)
        if (v[r][j] < lv) { lv = v[r][j]; li = j; }
      int midx = cg * 4 + li;
#pragma unroll
      for (int off = 1; off < 64; off <<= 1) {
        float ov = __shfl_xor(lv, off);
        int oi = __shfl_xor(midx, off);
        if (ov < lv || (ov == lv && oi < midx)) { lv = ov; midx = oi; }
      }
      if (cg == 0) nbrL[rg * 2 + r][it2] = midx;
      const bool mine = (cg == (midx >> 2));
      const int jw = midx & 3;
#pragma unroll
      for (int j = 0; j < 4; ++j)
        v[r][j] = (mine && j == jw) ? 3e38f : v[r][j];
    }
  }
  __syncthreads();
  // agg: thread = (row, 8-float chunk): 512 thr = 16 rows x 32 chunks
  {
    const int row = tid >> 5;
    const int q0 = (tid & 31) * 8;
    float4 a4[2] = {};
    for (int j = 0; j < kcnt; ++j) {
      const int nb = nbrL[row][j];
      const float* src = &xie[(size_t)(base + nb) * DD + q0];
      float4 v0 = *reinterpret_cast<const float4*>(&src[0]);
      float4 v1 = *reinterpret_cast<const float4*>(&src[4]);
      a4[0].x += v0.x; a4[0].y += v0.y; a4[0].z += v0.z; a4[0].w += v0.w;
      a4[1].x += v1.x; a4[1].y += v1.y; a4[1].z += v1.z; a4[1].w += v1.w;
    }
    const float sc = 1.0f / (float)kcnt;
    ushort_t ob[8];
#pragma unroll
    for (int q = 0; q < 2; ++q) {
      ob[q * 4 + 0] = f2bf(a4[q].x * sc);
      ob[q * 4 + 1] = f2bf(a4[q].y * sc);
      ob[q * 4 + 2] = f2bf(a4[q].z * sc);
      ob[q * 4 + 3] = f2bf(a4[q].w * sc);
    }
    ushort_t* dst = &A_bf[(size_t)(base + n0b + row) * 512 + 256 + q0];
    *reinterpret_cast<uint4*>(&dst[0]) = *reinterpret_cast<uint4*>(&ob[0]);
  }
  // cvtw tail: 512 blocks x first 256 thr = 131072 elems
  if (tid < 256) {
    const int id = blockIdx.x * 256 + tid;
    const int k = id >> 8;
    const int n = id & 255;
    float vw = (k < 256) ? Ws[(size_t)k * 256 + n] : Wn[(size_t)(k - 256) * 256 + n];
    B_bfT[(size_t)n * 512 + k] = f2bf(vw);
  }
}

// ---------------- K4: gep = relu(A_bf @ B_bfT^T + b) (R16 verbatim) -----------
__global__ __launch_bounds__(256) void k_gnn(const ushort_t* __restrict__ A_bf,
                                             const ushort_t* __restrict__ B_bfT,
                                             const float* __restrict__ bias,
                                             float* __restrict__ C,
                                             ushort_t* __restrict__ gep_bf) {
  __shared__ ushort_t As[64 * 72];
  __shared__ ushort_t Bs[64 * 72];
  const int tid = threadIdx.x;
  const int m0 = blockIdx.x * 64, n0 = blockIdx.y * 64;
  const int l = tid & 63, w = tid >> 6;
  const int mw = (w & 1) * 32, nw = (w >> 1) * 32;
  const int lr = tid >> 3, lq = tid & 7;
  f32x4 acc[2][2] = {};
  for (int kt = 0; kt < 8; ++kt) {
    const int kb = kt * 64;
#pragma unroll
    for (int s = 0; s < 2; ++s) {
      const int r = lr + s * 32;
      uint4 va = *reinterpret_cast<const uint4*>(&A_bf[(size_t)(m0 + r) * 512 + kb + lq * 8]);
      *reinterpret_cast<uint4*>(&As[r * 72 + lq * 8]) = va;
      uint4 vb = *reinterpret_cast<const uint4*>(&B_bfT[(size_t)(n0 + r) * 512 + kb + lq * 8]);
      *reinterpret_cast<uint4*>(&Bs[r * 72 + lq * 8]) = vb;
    }
    __syncthreads();
#pragma unroll
    for (int ks = 0; ks < 2; ++ks) {
      bf16x8 af[2], bf[2];
#pragma unroll
      for (int mi = 0; mi < 2; ++mi)
        af[mi] = *reinterpret_cast<const bf16x8*>(
            &As[(mw + mi * 16 + (l & 15)) * 72 + ks * 32 + (l >> 4) * 8]);
#pragma unroll
      for (int ni = 0; ni < 2; ++ni)
        bf[ni] = *reinterpret_cast<const bf16x8*>(
            &Bs[(nw + ni * 16 + (l & 15)) * 72 + ks * 32 + (l >> 4) * 8]);
#pragma unroll
      for (int mi = 0; mi < 2; ++mi)
#pragma unroll
        for (int ni = 0; ni < 2; ++ni)
          acc[mi][ni] = __builtin_amdgcn_mfma_f32_16x16x32_bf16(af[mi], bf[ni],
                                                                acc[mi][ni], 0, 0, 0);
    }
    __syncthreads();
  }
#pragma unroll
  for (int mi = 0; mi < 2; ++mi) {
    const int row_base = m0 + mw + mi * 16 + (l >> 4) * 4;
#pragma unroll
    for (int ni = 0; ni < 2; ++ni) {
      const int col = n0 + nw + ni * 16 + (l & 15);
      const float bv = bias[col];
#pragma unroll
      for (int r = 0; r < 4; ++r) {
        float v = acc[mi][ni][r] + bv;
        v = v > 0.0f ? v : 0.0f;
        C[(size_t)(row_base + r) * 256 + col] = v;
        gep_bf[(size_t)(row_base + r) * 256 + col] = f2bf(v);
      }
    }
  }
}

// ------- K5 v4: h partials, column-split, 2 blocks/CU (R16 verbatim) ----------
__global__ __launch_bounds__(256) void k_mlp1(const ushort_t* __restrict__ gep_bf,
                                              const float* __restrict__ W1,
                                              float* __restrict__ part) {
  __shared__ ushort_t WbT[2][256][40];       // [buf][col][32k + pad8]
  __shared__ ushort_t Ab[32][264];           // 32 rows x 256 k
  const int tid = threadIdx.x;
  const int b = blockIdx.x >> 1;
  const int ch = blockIdx.x & 1;
  const int l = tid & 63, w = tid >> 6;
#pragma unroll
  for (int i = 0; i < 4; ++i) {              // stage A (16 KB)
    int id = tid + i * 256;
    int m = id >> 5, dq8 = (id & 31) * 8;
    *reinterpret_cast<uint4*>(&Ab[m][dq8]) = *reinterpret_cast<const uint4*>(
        &gep_bf[((size_t)m * 256 + b) * 256 + dq8]);
  }
  const float* Wbase = W1 + (size_t)b * 256 * 512 + ch * 256 + tid;  // col = tid
  float wreg[32];
  auto WLOAD = [&](int s) {
#pragma unroll
    for (int kk = 0; kk < 32; ++kk)
      wreg[kk] = Wbase[(size_t)(s * 32 + kk) * 512];
  };
  auto WSTORE = [&](int buf) {
#pragma unroll
    for (int q = 0; q < 4; ++q) {
      ushort_t tmp[8];
#pragma unroll
      for (int j = 0; j < 8; ++j) tmp[j] = f2bf(wreg[q * 8 + j]);
      *reinterpret_cast<uint4*>(&WbT[buf][tid][q * 8]) =
          *reinterpret_cast<const uint4*>(tmp);
    }
  };
  WLOAD(0);
  WSTORE(0);
  __syncthreads();
  const int n0w = w * 64;
  f32x4 acc[2][4] = {};
  for (int s = 0; s < 8; ++s) {
    const int cur = s & 1;
    if (s < 7) WLOAD(s + 1);
    bf16x8 a[2], bw[4];
#pragma unroll
    for (int mi = 0; mi < 2; ++mi)
      a[mi] = *reinterpret_cast<const bf16x8*>(
          &Ab[mi * 16 + (l & 15)][s * 32 + (l >> 4) * 8]);
#pragma unroll
    for (int nf = 0; nf < 4; ++nf)
      bw[nf] = *reinterpret_cast<const bf16x8*>(
          &WbT[cur][n0w + nf * 16 + (l & 15)][(l >> 4) * 8]);
#pragma unroll
    for (int mi = 0; mi < 2; ++mi)
#pragma unroll
      for (int nf = 0; nf < 4; ++nf)
        acc[mi][nf] = __builtin_amdgcn_mfma_f32_16x16x32_bf16(a[mi], bw[nf],
                                                              acc[mi][nf], 0, 0, 0);
    if (s < 7) {
      WSTORE(cur ^ 1);
      __syncthreads();
    }
  }
#pragma unroll
  for (int mi = 0; mi < 2; ++mi)
#pragma unroll
    for (int nf = 0; nf < 4; ++nf) {
      const int col = ch * 256 + n0w + nf * 16 + (l & 15);
#pragma unroll
      for (int r = 0; r < 4; ++r) {
        const int m = mi * 16 + (l >> 4) * 4 + r;
        part[((size_t)b * 32 + m) * HH + col] = acc[mi][nf][r];
      }
    }
}

// ------- K6a: hpart (R16 verbatim) --------------------------------------------
__global__ __launch_bounds__(256) void k_hred(const float* __restrict__ part,
                                              float* __restrict__ hpart) {
  const int tid = threadIdx.x;
  const int m = blockIdx.x >> 3;           // 0..31
  const int s = blockIdx.x & 7;            // 0..7 (bb slice of 32)
  const int c0 = tid * 2;
  float a0 = 0.f, a1 = 0.f;
  for (int bb = s * 32; bb < s * 32 + 32; ++bb) {
    float2 v = *reinterpret_cast<const float2*>(&part[((size_t)bb * 32 + m) * 512 + c0]);
    a0 += v.x; a1 += v.y;
  }
  float2 o; o.x = a0; o.y = a1;
  *reinterpret_cast<float2*>(&hpart[((size_t)s * 32 + m) * 512 + c0]) = o;
}

// ------- K6b: out (R16 verbatim) ----------------------------------------------
__global__ __launch_bounds__(256) void k_out2(const float* __restrict__ hpart,
                                              const float* __restrict__ b1,
                                              const float* __restrict__ W2,
                                              const float* __restrict__ b2,
                                              float* __restrict__ outp) {
  __shared__ float red[4];
  const int tid = threadIdx.x;
  const int m = blockIdx.x;
  const int c0 = tid * 2;
  float a0 = 0.f, a1 = 0.f;
#pragma unroll
  for (int s = 0; s < 8; ++s) {
    float2 v = *reinterpret_cast<const float2*>(&hpart[((size_t)s * 32 + m) * 512 + c0]);
    a0 += v.x; a1 += v.y;
  }
  float h0 = a0 + b1[c0];
  float h1 = a1 + b1[c0 + 1];
  h0 = h0 > 0.f ? h0 : 0.f;
  h1 = h1 > 0.f ? h1 : 0.f;
  float val = h0 * W2[c0] + h1 * W2[c0 + 1];
#pragma unroll
  for (int off = 1; off < 64; off <<= 1) val += __shfl_xor(val, off);
  const int w = tid >> 6;
  if ((tid & 63) == 0) red[w] = val;
  __syncthreads();
  if (tid == 0) outp[m] = red[0] + red[1] + red[2] + red[3] + b2[0];
}

extern "C" void kernel_launch(void* const* d_in, const int* in_sizes, int n_in,
                              void* d_out, int out_size, void* d_ws, size_t ws_size,
                              hipStream_t stream) {
  const float* xi     = (const float*)d_in[0];
  const float* W_img  = (const float*)d_in[1];
  const float* b_img  = (const float*)d_in[2];
  const float* W_self = (const float*)d_in[3];
  const float* W_nbr  = (const float*)d_in[4];
  const float* b_gnn  = (const float*)d_in[5];
  const float* W1     = (const float*)d_in[6];
  const float* b1     = (const float*)d_in[7];
  const float* W2     = (const float*)d_in[8];
  const float* b2     = (const float*)d_in[9];
  const int*   kp     = (const int*)d_in[10];

  float* xie  = (float*)d_out;
  float* gep  = xie + (size_t)MM * DD;
  float* outp = gep + (size_t)MM * DD;

  float* ws   = (float*)d_ws;
  float* x2   = ws;                                   // 8,192 f
  float* part = ws + 8192;                            // 4,194,304 f
  float* xieT = part + (size_t)4194304;               // 2,097,152 f
  float* hpart = xieT + (size_t)2097152;              // 131,072 f
  ushort_t* A_bf   = (ushort_t*)(hpart + 131072);     // 8192*512 us
  ushort_t* B_bfT  = A_bf + (size_t)MM * 512;         // 131,072 us
  ushort_t* gep_bf = B_bfT + 131072;                  // 2,097,152 us

  k_enc  <<<MM / 16, 512, 0, stream>>>(xi, W_img, b_img, xie, A_bf, xieT, x2);
  k_dist <<<512, 512, 0, stream>>>(xie, xieT, x2, kp, A_bf, W_self, W_nbr, B_bfT);
  k_gnn  <<<dim3(128, 4), 256, 0, stream>>>(A_bf, B_bfT, b_gnn, gep, gep_bf);
  k_mlp1 <<<512, 256, 0, stream>>>(gep_bf, W1, part);
  k_hred <<<256, 256, 0, stream>>>(part, hpart);
  k_out2 <<<BB, 256, 0, stream>>>(hpart, b1, W2, b2, outp);
}